// Round 1
// baseline (12.514 us; speedup 1.0000x reference)
//
#include <hip/hip_runtime.h>
#include <hip/hip_bf16.h>
#include <math.h>

// SkipGram with sparse-mask structure:
// masked[i, j] = emb[i, j] iff (j - i) in OFFSETS = {0,12,19,24,28,31,34,36}
// score[b] = dot(masked[focus[b]], masked[context[b]])
//          = sum over pairs (i,j) with OFF[i] - OFF[j] == context[b] - focus[b]
//            of emb[f, f+OFF[i]] * emb[c, c+OFF[j]]
// out[b] = log_sigmoid(score[b])

#define VOCAB_SIZE 8192
#define EMBED_SIZE 8228

__device__ __forceinline__ float log_sigmoid_f(float x) {
    // stable: min(x,0) - log1p(exp(-|x|))
    return fminf(x, 0.0f) - log1pf(expf(-fabsf(x)));
}

__global__ __launch_bounds__(256) void skipgram_kernel(
    const int* __restrict__ focus,
    const int* __restrict__ context,
    const float* __restrict__ emb,
    float* __restrict__ out,
    int B)
{
    constexpr int OFF[8] = {0, 12, 19, 24, 28, 31, 34, 36};

    int b = blockIdx.x * blockDim.x + threadIdx.x;
    if (b >= B) return;

    int f = focus[b];
    int c = context[b];

    // Row pointers at the diagonal element (column == row index).
    // All 8 offset columns are in-bounds: f + 36 <= 8191 + 36 = 8227 < 8228.
    const float* rf = emb + (long long)f * EMBED_SIZE + f;
    const float* rc = emb + (long long)c * EMBED_SIZE + c;

    float ef[8], ec[8];
#pragma unroll
    for (int i = 0; i < 8; ++i) {
        ef[i] = rf[OFF[i]];
        ec[i] = rc[OFF[i]];
    }

    int d = c - f;
    float acc = 0.0f;
#pragma unroll
    for (int i = 0; i < 8; ++i) {
#pragma unroll
        for (int j = 0; j < 8; ++j) {
            // OFF[i] - OFF[j] is a compile-time constant after unrolling.
            acc += (d == (OFF[i] - OFF[j])) ? ef[i] * ec[j] : 0.0f;
        }
    }

    out[b] = log_sigmoid_f(acc);
}

extern "C" void kernel_launch(void* const* d_in, const int* in_sizes, int n_in,
                              void* d_out, int out_size, void* d_ws, size_t ws_size,
                              hipStream_t stream) {
    const int*   focus   = (const int*)d_in[0];
    const int*   context = (const int*)d_in[1];
    const float* emb     = (const float*)d_in[2];
    float*       out     = (float*)d_out;

    int B = in_sizes[0];  // 8192
    int block = 256;
    int grid = (B + block - 1) / block;
    skipgram_kernel<<<grid, block, 0, stream>>>(focus, context, emb, out, B);
}

// Round 2
// 9.394 us; speedup vs baseline: 1.3321x; 1.3321x over previous
//
#include <hip/hip_runtime.h>
#include <hip/hip_bf16.h>
#include <math.h>

// SkipGram with sparse-mask structure:
// masked[i, j] = emb[i, j] iff (j - i) in OFFSETS = {0,12,19,24,28,31,34,36}
// score[b] = dot(masked[focus[b]], masked[context[b]])
//          = sum over pairs (i,j) with OFF[i] - OFF[j] == context[b] - focus[b]
//            of emb[f, f+OFF[i]] * emb[c, c+OFF[j]]
// out[b] = log_sigmoid(score[b])
//
// Fast path: d = c - f is outside the offset-difference set for ~99.5% of
// random pairs -> score == 0 -> out = log_sigmoid(0) = -ln2. Only threads
// whose d is in the set do any row loads.

#define EMBED_SIZE 8228

__device__ __forceinline__ float log_sigmoid_f(float x) {
    // stable: min(x,0) - log1p(exp(-|x|))
    return fminf(x, 0.0f) - log1pf(expf(-fabsf(x)));
}

__global__ __launch_bounds__(256) void skipgram_kernel(
    const int* __restrict__ focus,
    const int* __restrict__ context,
    const float* __restrict__ emb,
    float* __restrict__ out,
    int B)
{
    constexpr int OFF[8] = {0, 12, 19, 24, 28, 31, 34, 36};
    // Bitmap of |OFF[i]-OFF[j]| values: {0,2,3,4,5,6,7,8,9,10,12,15,16,17,19,22,24,28,31,34,36}
    constexpr unsigned long long DIFF_MASK =
        (1ULL<<0)|(1ULL<<2)|(1ULL<<3)|(1ULL<<4)|(1ULL<<5)|(1ULL<<6)|(1ULL<<7)|
        (1ULL<<8)|(1ULL<<9)|(1ULL<<10)|(1ULL<<12)|(1ULL<<15)|(1ULL<<16)|(1ULL<<17)|
        (1ULL<<19)|(1ULL<<22)|(1ULL<<24)|(1ULL<<28)|(1ULL<<31)|(1ULL<<34)|(1ULL<<36);

    int b = blockIdx.x * blockDim.x + threadIdx.x;
    if (b >= B) return;

    int f = focus[b];
    int c = context[b];
    int d = c - f;
    int ad = abs(d);

    float result = -0.6931471805599453f;  // log_sigmoid(0) = -ln 2

    if (ad <= 36 && ((DIFF_MASK >> ad) & 1ULL)) {
        // Rare path (~0.5% of threads): do the masked-row dot product.
        const float* rf = emb + (long long)f * EMBED_SIZE + f;
        const float* rc = emb + (long long)c * EMBED_SIZE + c;

        float ef[8], ec[8];
#pragma unroll
        for (int i = 0; i < 8; ++i) {
            ef[i] = rf[OFF[i]];
            ec[i] = rc[OFF[i]];
        }

        float acc = 0.0f;
#pragma unroll
        for (int i = 0; i < 8; ++i) {
#pragma unroll
            for (int j = 0; j < 8; ++j) {
                acc += (d == (OFF[i] - OFF[j])) ? ef[i] * ec[j] : 0.0f;
            }
        }
        result = log_sigmoid_f(acc);
    }

    out[b] = result;
}

extern "C" void kernel_launch(void* const* d_in, const int* in_sizes, int n_in,
                              void* d_out, int out_size, void* d_ws, size_t ws_size,
                              hipStream_t stream) {
    const int*   focus   = (const int*)d_in[0];
    const int*   context = (const int*)d_in[1];
    const float* emb     = (const float*)d_in[2];
    float*       out     = (float*)d_out;

    int B = in_sizes[0];  // 8192
    int block = 256;
    int grid = (B + block - 1) / block;
    skipgram_kernel<<<grid, block, 0, stream>>>(focus, context, emb, out, B);
}